// Round 4
// baseline (7062.241 us; speedup 1.0000x reference)
//
#include <hip/hip_runtime.h>
#include <hip/hip_bf16.h>

// Problem constants (from setup_inputs)
#define N_NODES 20000
#define NANG 8
#define CH 64                      // in_size == out_size == 64
#define M_ROWS (NANG * N_NODES)    // 160000
#define E_EDGES (M_ROWS * 16)      // 2560000
#define K_CHEB 8
#define WK_STRIDE (NANG * CH * CH) // 32768 floats per weight[k]
#define BROWS 64                   // rows per bucket
#define NB (M_ROWS / BROWS)        // 2500 buckets

typedef short short8 __attribute__((ext_vector_type(8)));
typedef float f32x4 __attribute__((ext_vector_type(4)));

__device__ __forceinline__ float bf2f(ushort u) {
    return __uint_as_float((unsigned int)u << 16);
}

// ---------------- bucket build ----------------

__global__ void hist_kernel(const int* __restrict__ rows, int* __restrict__ bcount) {
    int e = blockIdx.x * 256 + threadIdx.x;
    if (e < E_EDGES) atomicAdd(&bcount[rows[e] >> 6], 1);
}

// single-block exclusive scan over NB=2500 bucket counts (3 per thread)
__global__ void bscan_kernel(const int* __restrict__ bcount, int* __restrict__ bstart) {
    __shared__ int s[1024];
    int t = threadIdx.x;
    int base = t * 3;
    int c0 = (base     < NB) ? bcount[base]     : 0;
    int c1 = (base + 1 < NB) ? bcount[base + 1] : 0;
    int c2 = (base + 2 < NB) ? bcount[base + 2] : 0;
    int tot = c0 + c1 + c2;
    s[t] = tot;
    __syncthreads();
    for (int off = 1; off < 1024; off <<= 1) {
        int v = (t >= off) ? s[t - off] : 0;
        __syncthreads();
        s[t] += v;
        __syncthreads();
    }
    int pre = s[t] - tot;
    if (base     < NB) bstart[base]     = pre;
    if (base + 1 < NB) bstart[base + 1] = pre + c0;
    if (base + 2 < NB) bstart[base + 2] = pre + c0 + c1;
    if (t == 1023) bstart[NB] = s[1023];
}

// edge -> bucket-ordered array; payload packs col (18b) | row-offset (6b)
__global__ void scatter_kernel(const int* __restrict__ rows, const int* __restrict__ cols,
                               const float* __restrict__ vals,
                               const int* __restrict__ bstart, int* __restrict__ bfill,
                               int2* __restrict__ bedges) {
    int e = blockIdx.x * 256 + threadIdx.x;
    if (e >= E_EDGES) return;
    int r = rows[e];
    int b = r >> 6;
    int p = atomicAdd(&bfill[b], 1);
    int packed = cols[e] | ((r & 63) << 18);
    bedges[bstart[b] + p] = make_int2(packed, __float_as_int(vals[e]));
}

// ---------------- small converts ----------------

__global__ void xconv_kernel(const float* __restrict__ x, ushort* __restrict__ xb) {
    int i = blockIdx.x * 256 + threadIdx.x;        // N_NODES*CH = 1.28M
    __hip_bfloat16 v = __float2bfloat16(x[i]);
    xb[i] = *(ushort*)&v;
}

// Wt[k][n][kk] = bf16(W[k][kk][n]); kk in [0,512), n in [0,64)
__global__ void wconv_kernel(const float* __restrict__ W, ushort* __restrict__ Wt) {
    int idx = blockIdx.x * 256 + threadIdx.x;      // 8*64*512 = 262144
    int kk = idx & 511;
    int n  = (idx >> 9) & 63;
    int k  = idx >> 15;
    __hip_bfloat16 v = __float2bfloat16(W[(size_t)k * WK_STRIDE + kk * 64 + n]);
    Wt[idx] = *(ushort*)&v;
}

// Wsum[n][ck] = bf16( sum_a W[0][a*64+ck][n] )   (gemm#0 collapses: tile(x)@W0 = x@Wsum)
__global__ void wsum_kernel(const float* __restrict__ W, ushort* __restrict__ Wsum) {
    int idx = blockIdx.x * 256 + threadIdx.x;      // 64*64
    int ck = idx & 63;
    int n  = idx >> 6;
    float s = 0.f;
#pragma unroll
    for (int a = 0; a < NANG; ++a) s += W[(a * 64 + ck) * 64 + n];
    __hip_bfloat16 v = __float2bfloat16(s);
    Wsum[idx] = *(ushort*)&v;
}

// ---------------- bucketed SpMM ----------------
// one block per bucket (64 rows). fp32 acc tile in LDS, ds_add_f32 accumulation.
// TIN_TILED: Tin is xb [N_NODES,64], index col % N_NODES.
// TSUB_MODE: 0 none, 1 normal [M,64], 2 tiled (xb).

template <int TIN_TILED, int TSUB_MODE>
__global__ __launch_bounds__(256) void spmm_bucket_kernel(
        const int* __restrict__ bstart, const int2* __restrict__ bedges,
        const ushort* __restrict__ Tin, const ushort* __restrict__ Tsub,
        ushort* __restrict__ Tout, float alpha, float beta) {
    __shared__ float acc[BROWS * CH];
    int tid = threadIdx.x;
    int lane = tid & 63;
    int b = blockIdx.x;

#pragma unroll
    for (int t = 0; t < 4; ++t) ((f32x4*)acc)[tid + t * 256] = (f32x4){0.f, 0.f, 0.f, 0.f};
    __syncthreads();

    int s = bstart[b];
    int e = bstart[b + 1];

    for (int j0 = s + (tid & ~63); j0 < e; j0 += 256) {
        int2 ed = bedges[min(j0 + lane, e - 1)];
        int cnt = min(64, e - j0);
        int jj = 0;
        for (; jj + 3 < cnt; jj += 4) {
            int p0 = __shfl(ed.x, jj),     w0 = __shfl(ed.y, jj);
            int p1 = __shfl(ed.x, jj + 1), w1 = __shfl(ed.y, jj + 1);
            int p2 = __shfl(ed.x, jj + 2), w2 = __shfl(ed.y, jj + 2);
            int p3 = __shfl(ed.x, jj + 3), w3 = __shfl(ed.y, jj + 3);
            unsigned c0 = (unsigned)p0 & 0x3ffffu;
            unsigned c1 = (unsigned)p1 & 0x3ffffu;
            unsigned c2 = (unsigned)p2 & 0x3ffffu;
            unsigned c3 = (unsigned)p3 & 0x3ffffu;
            if (TIN_TILED) { c0 %= N_NODES; c1 %= N_NODES; c2 %= N_NODES; c3 %= N_NODES; }
            float t0 = bf2f(Tin[(size_t)c0 * CH + lane]);
            float t1 = bf2f(Tin[(size_t)c1 * CH + lane]);
            float t2 = bf2f(Tin[(size_t)c2 * CH + lane]);
            float t3 = bf2f(Tin[(size_t)c3 * CH + lane]);
            __hip_atomic_fetch_add(&acc[((p0 >> 18) & 63) * CH + lane], __int_as_float(w0) * t0,
                                   __ATOMIC_RELAXED, __HIP_MEMORY_SCOPE_WORKGROUP);
            __hip_atomic_fetch_add(&acc[((p1 >> 18) & 63) * CH + lane], __int_as_float(w1) * t1,
                                   __ATOMIC_RELAXED, __HIP_MEMORY_SCOPE_WORKGROUP);
            __hip_atomic_fetch_add(&acc[((p2 >> 18) & 63) * CH + lane], __int_as_float(w2) * t2,
                                   __ATOMIC_RELAXED, __HIP_MEMORY_SCOPE_WORKGROUP);
            __hip_atomic_fetch_add(&acc[((p3 >> 18) & 63) * CH + lane], __int_as_float(w3) * t3,
                                   __ATOMIC_RELAXED, __HIP_MEMORY_SCOPE_WORKGROUP);
        }
        for (; jj < cnt; ++jj) {
            int p0 = __shfl(ed.x, jj), w0 = __shfl(ed.y, jj);
            unsigned c0 = (unsigned)p0 & 0x3ffffu;
            if (TIN_TILED) c0 %= N_NODES;
            float t0 = bf2f(Tin[(size_t)c0 * CH + lane]);
            __hip_atomic_fetch_add(&acc[((p0 >> 18) & 63) * CH + lane], __int_as_float(w0) * t0,
                                   __ATOMIC_RELAXED, __HIP_MEMORY_SCOPE_WORKGROUP);
        }
    }
    __syncthreads();

    int r0 = b * BROWS;
#pragma unroll
    for (int t = 0; t < 16; ++t) {
        int idx = tid + t * 256;                 // 0..4095
        int r = r0 + (idx >> 6);
        int c = idx & 63;
        float v = alpha * acc[idx];
        if (TSUB_MODE == 1) v += beta * bf2f(Tsub[(size_t)r * CH + c]);
        if (TSUB_MODE == 2) v += beta * bf2f(Tsub[(size_t)((unsigned)r % N_NODES) * CH + c]);
        __hip_bfloat16 o = __float2bfloat16(v);
        Tout[(size_t)r * CH + c] = *(ushort*)&o;
    }
}

// ---------------- GEMM via MFMA: out (+)= feat(T) @ Wk (+ bias) ----------------
// one wave = 16 nodes x 64 outs. A from bf16 T rows; B from Wt rows (L2-hot).
// C/D layout: col=lane&15, row=(lane>>4)*4+reg  [m89-verified].
// KSTEPS=16: T=[NANG*N,64] (K=512).  KSTEPS=2: T=xb [N,64] (K=64, Wsum).

template <int KSTEPS, int ACC>
__global__ __launch_bounds__(256) void gemm_mfma_kernel(
        const ushort* __restrict__ T,
        const ushort* __restrict__ Wp,    // [64][KSTEPS*32] bf16
        const float* __restrict__ bias,
        float* __restrict__ out) {        // [N_NODES, 64] fp32
    const int KSTRIDE = KSTEPS * 32;
    int wave = (blockIdx.x * 256 + threadIdx.x) >> 6;
    int l = threadIdx.x & 63;
    int m0 = wave * 16;
    if (m0 >= N_NODES) return;
    int lm = l & 15;
    int lq = l >> 4;

    f32x4 acc[4];
#pragma unroll
    for (int t = 0; t < 4; ++t) acc[t] = (f32x4){0.f, 0.f, 0.f, 0.f};

#pragma unroll
    for (int ks = 0; ks < KSTEPS; ++ks) {
        int a  = ks >> 1;
        int c0 = (ks & 1) * 32;
        short8 af = *(const short8*)(T + ((size_t)(a * N_NODES + m0 + lm)) * CH + c0 + lq * 8);
#pragma unroll
        for (int t = 0; t < 4; ++t) {
            short8 bfrag = *(const short8*)(Wp + (size_t)(t * 16 + lm) * KSTRIDE + ks * 32 + lq * 8);
            acc[t] = __builtin_amdgcn_mfma_f32_16x16x32_bf16(af, bfrag, acc[t], 0, 0, 0);
        }
    }

#pragma unroll
    for (int t = 0; t < 4; ++t) {
        int col = t * 16 + lm;
#pragma unroll
        for (int rI = 0; rI < 4; ++rI) {
            int row = m0 + lq * 4 + rI;
            size_t oi = (size_t)row * CH + col;
            if (ACC) out[oi] += acc[t][rI];
            else     out[oi] = acc[t][rI] + bias[col];
        }
    }
}

// ---------------- launch ----------------

extern "C" void kernel_launch(void* const* d_in, const int* in_sizes, int n_in,
                              void* d_out, int out_size, void* d_ws, size_t ws_size,
                              hipStream_t stream) {
    (void)in_sizes; (void)n_in; (void)out_size; (void)ws_size;
    const float* x       = (const float*)d_in[0];
    const float* ls_vals = (const float*)d_in[1];
    const float* weight  = (const float*)d_in[2];
    const float* bias    = (const float*)d_in[3];
    const int*   ls_rows = (const int*)d_in[4];
    const int*   ls_cols = (const int*)d_in[5];
    float* out = (float*)d_out;

    char* ws = (char*)d_ws;
    size_t off = 0;
    auto alloc = [&](size_t bytes) -> void* {
        void* p = ws + off;
        off += (bytes + 255) & ~(size_t)255;
        return p;
    };
    int*  bstart = (int*)alloc((NB + 1) * sizeof(int));
    int*  bcount = (int*)alloc(NB * sizeof(int));   // doubles as nothing else
    int*  bfill  = (int*)alloc(NB * sizeof(int));
    int2* bedges = (int2*)alloc((size_t)E_EDGES * sizeof(int2));
    ushort* Wt   = (ushort*)alloc((size_t)K_CHEB * 64 * 512 * sizeof(ushort));
    ushort* Wsum = (ushort*)alloc(64 * 64 * sizeof(ushort));
    ushort* xb   = (ushort*)alloc((size_t)N_NODES * CH * sizeof(ushort));
    ushort* T1   = (ushort*)alloc((size_t)M_ROWS * CH * sizeof(ushort));
    ushort* T2   = (ushort*)alloc((size_t)M_ROWS * CH * sizeof(ushort));
    ushort* T3   = (ushort*)alloc((size_t)M_ROWS * CH * sizeof(ushort));

    const int gemm_blocks = (N_NODES / 16 + 3) / 4;   // 313

    // bucket build
    hipMemsetAsync(bcount, 0, NB * sizeof(int), stream);
    hipMemsetAsync(bfill, 0, NB * sizeof(int), stream);
    hist_kernel<<<(E_EDGES + 255) / 256, 256, 0, stream>>>(ls_rows, bcount);
    bscan_kernel<<<1, 1024, 0, stream>>>(bcount, bstart);
    scatter_kernel<<<(E_EDGES + 255) / 256, 256, 0, stream>>>(
        ls_rows, ls_cols, ls_vals, bstart, bfill, bedges);

    // converts
    xconv_kernel<<<(N_NODES * CH) / 256, 256, 0, stream>>>(x, xb);
    wconv_kernel<<<(K_CHEB * 64 * 512) / 256, 256, 0, stream>>>(weight, Wt);
    wsum_kernel<<<(64 * 64) / 256, 256, 0, stream>>>(weight, Wsum);

    // k=0: out = x @ Wsum + bias
    gemm_mfma_kernel<2, 0><<<gemm_blocks, 256, 0, stream>>>(xb, Wsum, bias, out);

    // k=1: T1 = L @ tile(x); out += feat(T1) @ W1
    spmm_bucket_kernel<1, 0><<<NB, 256, 0, stream>>>(bstart, bedges, xb, xb, T1, 1.f, 0.f);
    gemm_mfma_kernel<16, 1><<<gemm_blocks, 256, 0, stream>>>(T1, Wt + (size_t)1 * 64 * 512, bias, out);

    // k=2: T2 = 2 L T1 - tile(x)
    spmm_bucket_kernel<0, 2><<<NB, 256, 0, stream>>>(bstart, bedges, T1, xb, T2, 2.f, -1.f);
    gemm_mfma_kernel<16, 1><<<gemm_blocks, 256, 0, stream>>>(T2, Wt + (size_t)2 * 64 * 512, bias, out);

    // k=3..7: Tn = 2 L Tc - Tp
    ushort* Tp = T1;
    ushort* Tc = T2;
    ushort* Tn = T3;
    for (int k = 3; k < K_CHEB; ++k) {
        spmm_bucket_kernel<0, 1><<<NB, 256, 0, stream>>>(bstart, bedges, Tc, Tp, Tn, 2.f, -1.f);
        gemm_mfma_kernel<16, 1><<<gemm_blocks, 256, 0, stream>>>(Tn, Wt + (size_t)k * 64 * 512, bias, out);
        ushort* t = Tp; Tp = Tc; Tc = Tn; Tn = t;
    }
}

// Round 5
// 1195.777 us; speedup vs baseline: 5.9060x; 5.9060x over previous
//
#include <hip/hip_runtime.h>
#include <hip/hip_bf16.h>

// Problem constants (from setup_inputs)
#define N_NODES 20000
#define NANG 8
#define CH 64                      // in_size == out_size == 64
#define M_ROWS (NANG * N_NODES)    // 160000
#define E_EDGES (M_ROWS * 16)      // 2560000
#define K_CHEB 8
#define WK_STRIDE (NANG * CH * CH) // 32768 floats per weight[k]
#define BROWS 64                   // rows per bucket
#define NB (M_ROWS / BROWS)        // 2500 buckets
#define NCHUNK 320
#define CHUNK (E_EDGES / NCHUNK)   // 8000
#define BCAP 1536                  // max edges/bucket (mean 1024, sd 32 -> 16 sigma)

typedef short short8 __attribute__((ext_vector_type(8)));
typedef float f32x4 __attribute__((ext_vector_type(4)));

__device__ __forceinline__ float bf2f(ushort u) {
    return __uint_as_float((unsigned int)u << 16);
}

// ---------------- deterministic bucket build (no global atomics) ----------------

// per-(chunk,bucket) histogram
__global__ __launch_bounds__(256) void count_kernel(const int* __restrict__ rows,
                                                    int* __restrict__ chunk_cnt) {
    __shared__ int h[NB];
    int c = blockIdx.x, tid = threadIdx.x;
    for (int i = tid; i < NB; i += 256) h[i] = 0;
    __syncthreads();
    int base = c * CHUNK;
    for (int i = tid; i < CHUNK; i += 256) atomicAdd(&h[rows[base + i] >> 6], 1);
    __syncthreads();
    for (int i = tid; i < NB; i += 256) chunk_cnt[(size_t)c * NB + i] = h[i];
}

__global__ void btotal_kernel(const int* __restrict__ chunk_cnt, int* __restrict__ btotal) {
    int b = blockIdx.x * 256 + threadIdx.x;
    if (b >= NB) return;
    int s = 0;
    for (int c = 0; c < NCHUNK; ++c) s += chunk_cnt[(size_t)c * NB + b];
    btotal[b] = s;
}

// single-block exclusive scan over NB bucket totals (3 per thread; 3072 >= 2500)
__global__ void bscan_kernel(const int* __restrict__ btotal, int* __restrict__ bstart) {
    __shared__ int s[1024];
    int t = threadIdx.x;
    int base = t * 3;
    int c0 = (base     < NB) ? btotal[base]     : 0;
    int c1 = (base + 1 < NB) ? btotal[base + 1] : 0;
    int c2 = (base + 2 < NB) ? btotal[base + 2] : 0;
    int tot = c0 + c1 + c2;
    s[t] = tot;
    __syncthreads();
    for (int off = 1; off < 1024; off <<= 1) {
        int v = (t >= off) ? s[t - off] : 0;
        __syncthreads();
        s[t] += v;
        __syncthreads();
    }
    int pre = s[t] - tot;
    if (base     < NB) bstart[base]     = pre;
    if (base + 1 < NB) bstart[base + 1] = pre + c0;
    if (base + 2 < NB) bstart[base + 2] = pre + c0 + c1;
    if (t == 1023) bstart[NB] = s[1023];
}

// chunk_cnt -> per-(chunk,bucket) write offsets, in place
__global__ void offs_kernel(int* __restrict__ chunk_cnt, const int* __restrict__ bstart) {
    int b = blockIdx.x * 256 + threadIdx.x;
    if (b >= NB) return;
    int run = bstart[b];
    for (int c = 0; c < NCHUNK; ++c) {
        int v = chunk_cnt[(size_t)c * NB + b];
        chunk_cnt[(size_t)c * NB + b] = run;
        run += v;
    }
}

// scatter into bucket-ordered streams (LDS-local offsets, sequential per-bucket writes)
__global__ __launch_bounds__(256) void scatter_kernel(
        const int* __restrict__ rows, const int* __restrict__ cols,
        const float* __restrict__ vals, const int* __restrict__ chunk_cnt,
        int2* __restrict__ bedges) {
    __shared__ int loff[NB];
    int c = blockIdx.x, tid = threadIdx.x;
    for (int i = tid; i < NB; i += 256) loff[i] = chunk_cnt[(size_t)c * NB + i];
    __syncthreads();
    int base = c * CHUNK;
    for (int i = tid; i < CHUNK; i += 256) {
        int e = base + i;
        int r = rows[e];
        int p = atomicAdd(&loff[r >> 6], 1);
        bedges[p] = make_int2(cols[e] | ((r & 63) << 18), __float_as_int(vals[e]));
    }
}

// per-bucket: sort edges by row, then by col within row; emit CSR row_start
__global__ __launch_bounds__(256) void bucket_sort_kernel(
        const int* __restrict__ bstart, const int2* __restrict__ bin,
        int2* __restrict__ bout, int* __restrict__ row_start) {
    __shared__ int2 eb[BCAP];
    __shared__ int2 ob[BCAP];
    __shared__ int cnt[BROWS];
    __shared__ int pref[BROWS + 1];
    __shared__ int fill[BROWS];
    int b = blockIdx.x, tid = threadIdx.x;
    int s = bstart[b], e = bstart[b + 1];
    int n = min(e - s, BCAP);
    if (tid < BROWS) cnt[tid] = 0;
    __syncthreads();
    for (int i = tid; i < n; i += 256) {
        int2 ed = bin[s + i];
        eb[i] = ed;
        atomicAdd(&cnt[(ed.x >> 18) & 63], 1);
    }
    __syncthreads();
    if (tid == 0) {
        int run = 0;
        for (int r = 0; r < BROWS; ++r) { pref[r] = run; run += cnt[r]; }
        pref[BROWS] = run;
    }
    __syncthreads();
    if (tid < BROWS) fill[tid] = pref[tid];
    __syncthreads();
    for (int i = tid; i < n; i += 256) {
        int2 ed = eb[i];
        int p = atomicAdd(&fill[(ed.x >> 18) & 63], 1);
        ob[p] = make_int2(ed.x & 0x3ffff, ed.y);
    }
    __syncthreads();
    if (tid < BROWS) {            // insertion-sort each row segment by col
        int lo = pref[tid], hi = pref[tid + 1];
        for (int i = lo + 1; i < hi; ++i) {
            int2 key = ob[i];
            int j = i - 1;
            while (j >= lo && ob[j].x > key.x) { ob[j + 1] = ob[j]; --j; }
            ob[j + 1] = key;
        }
    }
    __syncthreads();
    for (int i = tid; i < n; i += 256) bout[s + i] = ob[i];
    if (tid < BROWS) row_start[b * BROWS + tid] = s + pref[tid];
    if (b == NB - 1 && tid == 0) row_start[M_ROWS] = e;
}

// ---------------- small converts ----------------

__global__ void xconv_kernel(const float* __restrict__ x, ushort* __restrict__ xb) {
    int i = blockIdx.x * 256 + threadIdx.x;
    __hip_bfloat16 v = __float2bfloat16(x[i]);
    xb[i] = *(ushort*)&v;
}

// Wt[k][n][kk] = bf16(W[k][kk][n])
__global__ void wconv_kernel(const float* __restrict__ W, ushort* __restrict__ Wt) {
    int idx = blockIdx.x * 256 + threadIdx.x;
    int kk = idx & 511;
    int n  = (idx >> 9) & 63;
    int k  = idx >> 15;
    __hip_bfloat16 v = __float2bfloat16(W[(size_t)k * WK_STRIDE + kk * 64 + n]);
    Wt[idx] = *(ushort*)&v;
}

// Wsum[n][ck] = bf16( sum_a W[0][a*64+ck][n] )  (tile(x)@W0 == x@Wsum)
__global__ void wsum_kernel(const float* __restrict__ W, ushort* __restrict__ Wsum) {
    int idx = blockIdx.x * 256 + threadIdx.x;
    int ck = idx & 63;
    int n  = idx >> 6;
    float s = 0.f;
#pragma unroll
    for (int a = 0; a < NANG; ++a) s += W[(a * 64 + ck) * 64 + n];
    __hip_bfloat16 v = __float2bfloat16(s);
    Wsum[idx] = *(ushort*)&v;
}

// ---------------- SpMM: row-per-wave gather (edges col-sorted per row) ----------------
// TIN_TILED: Tin is xb [N,64], col % N_NODES. TSUB_MODE: 0 none, 1 [M,64], 2 xb tiled.

template <int TIN_TILED, int TSUB_MODE>
__global__ __launch_bounds__(256) void spmm_kernel(
        const int* __restrict__ row_start, const int2* __restrict__ edges,
        const ushort* __restrict__ Tin, const ushort* __restrict__ Tsub,
        ushort* __restrict__ Tout, float alpha, float beta) {
    int r = (blockIdx.x * 256 + threadIdx.x) >> 6;
    int lane = threadIdx.x & 63;
    if (r >= M_ROWS) return;
    int s = row_start[r];
    int e = row_start[r + 1];
    float acc = 0.f;
    int j = s;
    for (; j + 3 < e; j += 4) {
        int2 e0 = edges[j];
        int2 e1 = edges[j + 1];
        int2 e2 = edges[j + 2];
        int2 e3 = edges[j + 3];
        unsigned c0 = (unsigned)e0.x, c1 = (unsigned)e1.x;
        unsigned c2 = (unsigned)e2.x, c3 = (unsigned)e3.x;
        if (TIN_TILED) { c0 %= N_NODES; c1 %= N_NODES; c2 %= N_NODES; c3 %= N_NODES; }
        float t0 = bf2f(Tin[(size_t)c0 * CH + lane]);
        float t1 = bf2f(Tin[(size_t)c1 * CH + lane]);
        float t2 = bf2f(Tin[(size_t)c2 * CH + lane]);
        float t3 = bf2f(Tin[(size_t)c3 * CH + lane]);
        acc = fmaf(__int_as_float(e0.y), t0, acc);
        acc = fmaf(__int_as_float(e1.y), t1, acc);
        acc = fmaf(__int_as_float(e2.y), t2, acc);
        acc = fmaf(__int_as_float(e3.y), t3, acc);
    }
    for (; j < e; ++j) {
        int2 e0 = edges[j];
        unsigned c0 = (unsigned)e0.x;
        if (TIN_TILED) c0 %= N_NODES;
        acc = fmaf(__int_as_float(e0.y), bf2f(Tin[(size_t)c0 * CH + lane]), acc);
    }
    size_t oi = (size_t)r * CH + lane;
    float v = alpha * acc;
    if (TSUB_MODE == 1) v += beta * bf2f(Tsub[oi]);
    if (TSUB_MODE == 2) v += beta * bf2f(Tsub[(size_t)((unsigned)r % N_NODES) * CH + lane]);
    __hip_bfloat16 o = __float2bfloat16(v);
    Tout[oi] = *(ushort*)&o;
}

// ---------------- GEMM via MFMA: out (+)= feat(T) @ Wk (+ bias) ----------------
// C/D layout: col=lane&15, row=(lane>>4)*4+reg  [m89-verified]

template <int KSTEPS, int ACC>
__global__ __launch_bounds__(256) void gemm_mfma_kernel(
        const ushort* __restrict__ T,
        const ushort* __restrict__ Wp,    // [64][KSTEPS*32] bf16
        const float* __restrict__ bias,
        float* __restrict__ out) {        // [N_NODES, 64] fp32
    const int KSTRIDE = KSTEPS * 32;
    int wave = (blockIdx.x * 256 + threadIdx.x) >> 6;
    int l = threadIdx.x & 63;
    int m0 = wave * 16;
    if (m0 >= N_NODES) return;
    int lm = l & 15;
    int lq = l >> 4;

    f32x4 acc[4];
#pragma unroll
    for (int t = 0; t < 4; ++t) acc[t] = (f32x4){0.f, 0.f, 0.f, 0.f};

#pragma unroll
    for (int ks = 0; ks < KSTEPS; ++ks) {
        int a  = ks >> 1;
        int c0 = (ks & 1) * 32;
        short8 af = *(const short8*)(T + ((size_t)(a * N_NODES + m0 + lm)) * CH + c0 + lq * 8);
#pragma unroll
        for (int t = 0; t < 4; ++t) {
            short8 bfrag = *(const short8*)(Wp + (size_t)(t * 16 + lm) * KSTRIDE + ks * 32 + lq * 8);
            acc[t] = __builtin_amdgcn_mfma_f32_16x16x32_bf16(af, bfrag, acc[t], 0, 0, 0);
        }
    }

#pragma unroll
    for (int t = 0; t < 4; ++t) {
        int col = t * 16 + lm;
#pragma unroll
        for (int rI = 0; rI < 4; ++rI) {
            int row = m0 + lq * 4 + rI;
            size_t oi = (size_t)row * CH + col;
            if (ACC) out[oi] += acc[t][rI];
            else     out[oi] = acc[t][rI] + bias[col];
        }
    }
}

// ---------------- launch ----------------

extern "C" void kernel_launch(void* const* d_in, const int* in_sizes, int n_in,
                              void* d_out, int out_size, void* d_ws, size_t ws_size,
                              hipStream_t stream) {
    (void)in_sizes; (void)n_in; (void)out_size; (void)ws_size;
    const float* x       = (const float*)d_in[0];
    const float* ls_vals = (const float*)d_in[1];
    const float* weight  = (const float*)d_in[2];
    const float* bias    = (const float*)d_in[3];
    const int*   ls_rows = (const int*)d_in[4];
    const int*   ls_cols = (const int*)d_in[5];
    float* out = (float*)d_out;

    char* ws = (char*)d_ws;
    size_t off = 0;
    auto alloc = [&](size_t bytes) -> void* {
        void* p = ws + off;
        off += (bytes + 255) & ~(size_t)255;
        return p;
    };
    int*  chunk_cnt = (int*)alloc((size_t)NCHUNK * NB * sizeof(int));
    int*  btotal    = (int*)alloc(NB * sizeof(int));
    int*  bstart    = (int*)alloc((NB + 1) * sizeof(int));
    int*  row_start = (int*)alloc((M_ROWS + 1) * sizeof(int));
    int2* bedges    = (int2*)alloc((size_t)E_EDGES * sizeof(int2));
    int2* bedges2   = (int2*)alloc((size_t)E_EDGES * sizeof(int2));
    ushort* Wt   = (ushort*)alloc((size_t)K_CHEB * 64 * 512 * sizeof(ushort));
    ushort* Wsum = (ushort*)alloc(64 * 64 * sizeof(ushort));
    ushort* xb   = (ushort*)alloc((size_t)N_NODES * CH * sizeof(ushort));
    ushort* T1   = (ushort*)alloc((size_t)M_ROWS * CH * sizeof(ushort));
    ushort* T2   = (ushort*)alloc((size_t)M_ROWS * CH * sizeof(ushort));
    ushort* T3   = (ushort*)alloc((size_t)M_ROWS * CH * sizeof(ushort));

    const int gemm_blocks = (N_NODES / 16 + 3) / 4;   // 313
    const int spmm_blocks = M_ROWS / 4;               // 40000

    // deterministic bucket build + per-bucket row/col sort
    count_kernel<<<NCHUNK, 256, 0, stream>>>(ls_rows, chunk_cnt);
    btotal_kernel<<<(NB + 255) / 256, 256, 0, stream>>>(chunk_cnt, btotal);
    bscan_kernel<<<1, 1024, 0, stream>>>(btotal, bstart);
    offs_kernel<<<(NB + 255) / 256, 256, 0, stream>>>(chunk_cnt, bstart);
    scatter_kernel<<<NCHUNK, 256, 0, stream>>>(ls_rows, ls_cols, ls_vals, chunk_cnt, bedges);
    bucket_sort_kernel<<<NB, 256, 0, stream>>>(bstart, bedges, bedges2, row_start);

    // converts
    xconv_kernel<<<(N_NODES * CH) / 256, 256, 0, stream>>>(x, xb);
    wconv_kernel<<<(K_CHEB * 64 * 512) / 256, 256, 0, stream>>>(weight, Wt);
    wsum_kernel<<<(64 * 64) / 256, 256, 0, stream>>>(weight, Wsum);

    // k=0: out = x @ Wsum + bias
    gemm_mfma_kernel<2, 0><<<gemm_blocks, 256, 0, stream>>>(xb, Wsum, bias, out);

    // k=1: T1 = L @ tile(x)  (gathers from L2-resident xb); out += feat(T1) @ W1
    spmm_kernel<1, 0><<<spmm_blocks, 256, 0, stream>>>(row_start, bedges2, xb, xb, T1, 1.f, 0.f);
    gemm_mfma_kernel<16, 1><<<gemm_blocks, 256, 0, stream>>>(T1, Wt + (size_t)1 * 64 * 512, bias, out);

    // k=2: T2 = 2 L T1 - tile(x)
    spmm_kernel<0, 2><<<spmm_blocks, 256, 0, stream>>>(row_start, bedges2, T1, xb, T2, 2.f, -1.f);
    gemm_mfma_kernel<16, 1><<<gemm_blocks, 256, 0, stream>>>(T2, Wt + (size_t)2 * 64 * 512, bias, out);

    // k=3..7: Tn = 2 L Tc - Tp
    ushort* Tp = T1;
    ushort* Tc = T2;
    ushort* Tn = T3;
    for (int k = 3; k < K_CHEB; ++k) {
        spmm_kernel<0, 1><<<spmm_blocks, 256, 0, stream>>>(row_start, bedges2, Tc, Tp, Tn, 2.f, -1.f);
        gemm_mfma_kernel<16, 1><<<gemm_blocks, 256, 0, stream>>>(Tn, Wt + (size_t)k * 64 * 512, bias, out);
        ushort* t = Tp; Tp = Tc; Tc = Tn; Tn = t;
    }
}

// Round 6
// 878.555 us; speedup vs baseline: 8.0385x; 1.3611x over previous
//
#include <hip/hip_runtime.h>
#include <hip/hip_bf16.h>

// Problem constants (from setup_inputs)
#define N_NODES 20000
#define NANG 8
#define CH 64                      // in_size == out_size == 64
#define M_ROWS (NANG * N_NODES)    // 160000
#define E_EDGES (M_ROWS * 16)      // 2560000
#define K_CHEB 8
#define WK_STRIDE (NANG * CH * CH) // 32768 floats per weight[k]
#define BROWS 64                   // rows per bucket
#define NB (M_ROWS / BROWS)        // 2500 buckets
#define NCHUNK 320
#define CHUNK (E_EDGES / NCHUNK)   // 8000
#define BCAP 1536                  // max edges/bucket (mean 1024, sd 32 -> 16 sigma)

typedef short short8 __attribute__((ext_vector_type(8)));
typedef float f32x4 __attribute__((ext_vector_type(4)));

__device__ __forceinline__ float bf2f(ushort u) {
    return __uint_as_float((unsigned int)u << 16);
}

// ---------------- deterministic bucket build (no global atomics) ----------------

// per-(chunk,bucket) histogram
__global__ __launch_bounds__(256) void count_kernel(const int* __restrict__ rows,
                                                    int* __restrict__ chunk_cnt) {
    __shared__ int h[NB];
    int c = blockIdx.x, tid = threadIdx.x;
    for (int i = tid; i < NB; i += 256) h[i] = 0;
    __syncthreads();
    int base = c * CHUNK;
    for (int i = tid; i < CHUNK; i += 256) atomicAdd(&h[rows[base + i] >> 6], 1);
    __syncthreads();
    for (int i = tid; i < NB; i += 256) chunk_cnt[(size_t)c * NB + i] = h[i];
}

__global__ void btotal_kernel(const int* __restrict__ chunk_cnt, int* __restrict__ btotal) {
    int b = blockIdx.x * 256 + threadIdx.x;
    if (b >= NB) return;
    int s = 0;
    for (int c = 0; c < NCHUNK; ++c) s += chunk_cnt[(size_t)c * NB + b];
    btotal[b] = s;
}

// single-block exclusive scan over NB bucket totals (3 per thread; 3072 >= 2500)
__global__ void bscan_kernel(const int* __restrict__ btotal, int* __restrict__ bstart) {
    __shared__ int s[1024];
    int t = threadIdx.x;
    int base = t * 3;
    int c0 = (base     < NB) ? btotal[base]     : 0;
    int c1 = (base + 1 < NB) ? btotal[base + 1] : 0;
    int c2 = (base + 2 < NB) ? btotal[base + 2] : 0;
    int tot = c0 + c1 + c2;
    s[t] = tot;
    __syncthreads();
    for (int off = 1; off < 1024; off <<= 1) {
        int v = (t >= off) ? s[t - off] : 0;
        __syncthreads();
        s[t] += v;
        __syncthreads();
    }
    int pre = s[t] - tot;
    if (base     < NB) bstart[base]     = pre;
    if (base + 1 < NB) bstart[base + 1] = pre + c0;
    if (base + 2 < NB) bstart[base + 2] = pre + c0 + c1;
    if (t == 1023) bstart[NB] = s[1023];
}

// chunk_cnt -> per-(chunk,bucket) write offsets, in place
__global__ void offs_kernel(int* __restrict__ chunk_cnt, const int* __restrict__ bstart) {
    int b = blockIdx.x * 256 + threadIdx.x;
    if (b >= NB) return;
    int run = bstart[b];
    for (int c = 0; c < NCHUNK; ++c) {
        int v = chunk_cnt[(size_t)c * NB + b];
        chunk_cnt[(size_t)c * NB + b] = run;
        run += v;
    }
}

// scatter into bucket-ordered streams (LDS-local offsets, sequential per-bucket writes)
__global__ __launch_bounds__(256) void scatter_kernel(
        const int* __restrict__ rows, const int* __restrict__ cols,
        const float* __restrict__ vals, const int* __restrict__ chunk_cnt,
        int2* __restrict__ bedges) {
    __shared__ int loff[NB];
    int c = blockIdx.x, tid = threadIdx.x;
    for (int i = tid; i < NB; i += 256) loff[i] = chunk_cnt[(size_t)c * NB + i];
    __syncthreads();
    int base = c * CHUNK;
    for (int i = tid; i < CHUNK; i += 256) {
        int e = base + i;
        int r = rows[e];
        int p = atomicAdd(&loff[r >> 6], 1);
        bedges[p] = make_int2(cols[e] | ((r & 63) << 18), __float_as_int(vals[e]));
    }
}

// per-bucket: sort edges by row, then by col within row; emit CSR row_start
__global__ __launch_bounds__(256) void bucket_sort_kernel(
        const int* __restrict__ bstart, const int2* __restrict__ bin,
        int2* __restrict__ bout, int* __restrict__ row_start) {
    __shared__ int2 eb[BCAP];
    __shared__ int2 ob[BCAP];
    __shared__ int cnt[BROWS];
    __shared__ int pref[BROWS + 1];
    __shared__ int fill[BROWS];
    int b = blockIdx.x, tid = threadIdx.x;
    int s = bstart[b], e = bstart[b + 1];
    int n = min(e - s, BCAP);
    if (tid < BROWS) cnt[tid] = 0;
    __syncthreads();
    for (int i = tid; i < n; i += 256) {
        int2 ed = bin[s + i];
        eb[i] = ed;
        atomicAdd(&cnt[(ed.x >> 18) & 63], 1);
    }
    __syncthreads();
    if (tid == 0) {
        int run = 0;
        for (int r = 0; r < BROWS; ++r) { pref[r] = run; run += cnt[r]; }
        pref[BROWS] = run;
    }
    __syncthreads();
    if (tid < BROWS) fill[tid] = pref[tid];
    __syncthreads();
    for (int i = tid; i < n; i += 256) {
        int2 ed = eb[i];
        int p = atomicAdd(&fill[(ed.x >> 18) & 63], 1);
        ob[p] = make_int2(ed.x & 0x3ffff, ed.y);
    }
    __syncthreads();
    if (tid < BROWS) {            // insertion-sort each row segment by col
        int lo = pref[tid], hi = pref[tid + 1];
        for (int i = lo + 1; i < hi; ++i) {
            int2 key = ob[i];
            int j = i - 1;
            while (j >= lo && ob[j].x > key.x) { ob[j + 1] = ob[j]; --j; }
            ob[j + 1] = key;
        }
    }
    __syncthreads();
    for (int i = tid; i < n; i += 256) bout[s + i] = ob[i];
    if (tid < BROWS) row_start[b * BROWS + tid] = s + pref[tid];
    if (b == NB - 1 && tid == 0) row_start[M_ROWS] = e;
}

// ---------------- small converts ----------------

__global__ void xconv_kernel(const float* __restrict__ x, ushort* __restrict__ xb) {
    int i = blockIdx.x * 256 + threadIdx.x;
    __hip_bfloat16 v = __float2bfloat16(x[i]);
    xb[i] = *(ushort*)&v;
}

// Wt[k][n][kk] = bf16(W[k][kk][n])
__global__ void wconv_kernel(const float* __restrict__ W, ushort* __restrict__ Wt) {
    int idx = blockIdx.x * 256 + threadIdx.x;
    int kk = idx & 511;
    int n  = (idx >> 9) & 63;
    int k  = idx >> 15;
    __hip_bfloat16 v = __float2bfloat16(W[(size_t)k * WK_STRIDE + kk * 64 + n]);
    Wt[idx] = *(ushort*)&v;
}

// Wsum[n][ck] = bf16( sum_a W[0][a*64+ck][n] )  (tile(x)@W0 == x@Wsum)
__global__ void wsum_kernel(const float* __restrict__ W, ushort* __restrict__ Wsum) {
    int idx = blockIdx.x * 256 + threadIdx.x;
    int ck = idx & 63;
    int n  = idx >> 6;
    float s = 0.f;
#pragma unroll
    for (int a = 0; a < NANG; ++a) s += W[(a * 64 + ck) * 64 + n];
    __hip_bfloat16 v = __float2bfloat16(s);
    Wsum[idx] = *(ushort*)&v;
}

// ---------------- SpMM: row-per-wave gather, readlane edge broadcast ----------------
// One 128B coalesced load pulls 16 edges; readlane(i) makes (col,w) wave-uniform
// SGPRs; 16 independent gathers issue per batch (MLP 16 vs unroll-4's 4).
// TIN_TILED: Tin is xb [N,64], col % N_NODES. TSUB_MODE: 0 none, 1 [M,64], 2 xb tiled.

template <int TIN_TILED, int TSUB_MODE>
__global__ __launch_bounds__(256) void spmm_kernel(
        const int* __restrict__ row_start, const int2* __restrict__ edges,
        const ushort* __restrict__ Tin, const ushort* __restrict__ Tsub,
        ushort* __restrict__ Tout, float alpha, float beta) {
    int r = (blockIdx.x * 256 + threadIdx.x) >> 6;
    int lane = threadIdx.x & 63;
    if (r >= M_ROWS) return;
    int s = row_start[r];
    int e = row_start[r + 1];
    float acc = 0.f;
    for (int base = s; base < e; base += 16) {
        int idx = min(base + (lane & 15), e - 1);
        int2 ed = edges[idx];                 // 16 edges, 128B coalesced (4x dup)
#pragma unroll
        for (int i = 0; i < 16; ++i) {
            int   col = __builtin_amdgcn_readlane(ed.x, i);
            float w   = __int_as_float(__builtin_amdgcn_readlane(ed.y, i));
            if (base + i >= e) w = 0.f;       // clamped dup edge contributes 0
            unsigned c = (unsigned)col;
            if (TIN_TILED) c %= N_NODES;
            float t = bf2f(Tin[(size_t)c * CH + lane]);
            acc = fmaf(w, t, acc);
        }
    }
    size_t oi = (size_t)r * CH + lane;
    float v = alpha * acc;
    if (TSUB_MODE == 1) v += beta * bf2f(Tsub[oi]);
    if (TSUB_MODE == 2) v += beta * bf2f(Tsub[(size_t)((unsigned)r % N_NODES) * CH + lane]);
    __hip_bfloat16 o = __float2bfloat16(v);
    Tout[oi] = *(ushort*)&o;
}

// ---------------- GEMM via MFMA: out (+)= feat(T) @ Wk (+ bias) ----------------
// C/D layout: col=lane&15, row=(lane>>4)*4+reg  [m89-verified]

template <int KSTEPS, int ACC>
__global__ __launch_bounds__(256) void gemm_mfma_kernel(
        const ushort* __restrict__ T,
        const ushort* __restrict__ Wp,    // [64][KSTEPS*32] bf16
        const float* __restrict__ bias,
        float* __restrict__ out) {        // [N_NODES, 64] fp32
    const int KSTRIDE = KSTEPS * 32;
    int wave = (blockIdx.x * 256 + threadIdx.x) >> 6;
    int l = threadIdx.x & 63;
    int m0 = wave * 16;
    if (m0 >= N_NODES) return;
    int lm = l & 15;
    int lq = l >> 4;

    f32x4 acc[4];
#pragma unroll
    for (int t = 0; t < 4; ++t) acc[t] = (f32x4){0.f, 0.f, 0.f, 0.f};

#pragma unroll
    for (int ks = 0; ks < KSTEPS; ++ks) {
        int a  = ks >> 1;
        int c0 = (ks & 1) * 32;
        short8 af = *(const short8*)(T + ((size_t)(a * N_NODES + m0 + lm)) * CH + c0 + lq * 8);
#pragma unroll
        for (int t = 0; t < 4; ++t) {
            short8 bfrag = *(const short8*)(Wp + (size_t)(t * 16 + lm) * KSTRIDE + ks * 32 + lq * 8);
            acc[t] = __builtin_amdgcn_mfma_f32_16x16x32_bf16(af, bfrag, acc[t], 0, 0, 0);
        }
    }

#pragma unroll
    for (int t = 0; t < 4; ++t) {
        int col = t * 16 + lm;
#pragma unroll
        for (int rI = 0; rI < 4; ++rI) {
            int row = m0 + lq * 4 + rI;
            size_t oi = (size_t)row * CH + col;
            if (ACC) out[oi] += acc[t][rI];
            else     out[oi] = acc[t][rI] + bias[col];
        }
    }
}

// ---------------- launch ----------------

extern "C" void kernel_launch(void* const* d_in, const int* in_sizes, int n_in,
                              void* d_out, int out_size, void* d_ws, size_t ws_size,
                              hipStream_t stream) {
    (void)in_sizes; (void)n_in; (void)out_size; (void)ws_size;
    const float* x       = (const float*)d_in[0];
    const float* ls_vals = (const float*)d_in[1];
    const float* weight  = (const float*)d_in[2];
    const float* bias    = (const float*)d_in[3];
    const int*   ls_rows = (const int*)d_in[4];
    const int*   ls_cols = (const int*)d_in[5];
    float* out = (float*)d_out;

    char* ws = (char*)d_ws;
    size_t off = 0;
    auto alloc = [&](size_t bytes) -> void* {
        void* p = ws + off;
        off += (bytes + 255) & ~(size_t)255;
        return p;
    };
    int*  chunk_cnt = (int*)alloc((size_t)NCHUNK * NB * sizeof(int));
    int*  btotal    = (int*)alloc(NB * sizeof(int));
    int*  bstart    = (int*)alloc((NB + 1) * sizeof(int));
    int*  row_start = (int*)alloc((M_ROWS + 1) * sizeof(int));
    int2* bedges    = (int2*)alloc((size_t)E_EDGES * sizeof(int2));
    int2* bedges2   = (int2*)alloc((size_t)E_EDGES * sizeof(int2));
    ushort* Wt   = (ushort*)alloc((size_t)K_CHEB * 64 * 512 * sizeof(ushort));
    ushort* Wsum = (ushort*)alloc(64 * 64 * sizeof(ushort));
    ushort* xb   = (ushort*)alloc((size_t)N_NODES * CH * sizeof(ushort));
    ushort* T1   = (ushort*)alloc((size_t)M_ROWS * CH * sizeof(ushort));
    ushort* T2   = (ushort*)alloc((size_t)M_ROWS * CH * sizeof(ushort));
    ushort* T3   = (ushort*)alloc((size_t)M_ROWS * CH * sizeof(ushort));

    const int gemm_blocks = (N_NODES / 16 + 3) / 4;   // 313
    const int spmm_blocks = M_ROWS / 4;               // 40000

    // deterministic bucket build + per-bucket row/col sort
    count_kernel<<<NCHUNK, 256, 0, stream>>>(ls_rows, chunk_cnt);
    btotal_kernel<<<(NB + 255) / 256, 256, 0, stream>>>(chunk_cnt, btotal);
    bscan_kernel<<<1, 1024, 0, stream>>>(btotal, bstart);
    offs_kernel<<<(NB + 255) / 256, 256, 0, stream>>>(chunk_cnt, bstart);
    scatter_kernel<<<NCHUNK, 256, 0, stream>>>(ls_rows, ls_cols, ls_vals, chunk_cnt, bedges);
    bucket_sort_kernel<<<NB, 256, 0, stream>>>(bstart, bedges, bedges2, row_start);

    // converts
    xconv_kernel<<<(N_NODES * CH) / 256, 256, 0, stream>>>(x, xb);
    wconv_kernel<<<(K_CHEB * 64 * 512) / 256, 256, 0, stream>>>(weight, Wt);
    wsum_kernel<<<(64 * 64) / 256, 256, 0, stream>>>(weight, Wsum);

    // k=0: out = x @ Wsum + bias
    gemm_mfma_kernel<2, 0><<<gemm_blocks, 256, 0, stream>>>(xb, Wsum, bias, out);

    // k=1: T1 = L @ tile(x)  (gathers from L2-resident xb); out += feat(T1) @ W1
    spmm_kernel<1, 0><<<spmm_blocks, 256, 0, stream>>>(row_start, bedges2, xb, xb, T1, 1.f, 0.f);
    gemm_mfma_kernel<16, 1><<<gemm_blocks, 256, 0, stream>>>(T1, Wt + (size_t)1 * 64 * 512, bias, out);

    // k=2: T2 = 2 L T1 - tile(x)
    spmm_kernel<0, 2><<<spmm_blocks, 256, 0, stream>>>(row_start, bedges2, T1, xb, T2, 2.f, -1.f);
    gemm_mfma_kernel<16, 1><<<gemm_blocks, 256, 0, stream>>>(T2, Wt + (size_t)2 * 64 * 512, bias, out);

    // k=3..7: Tn = 2 L Tc - Tp
    ushort* Tp = T1;
    ushort* Tc = T2;
    ushort* Tn = T3;
    for (int k = 3; k < K_CHEB; ++k) {
        spmm_kernel<0, 1><<<spmm_blocks, 256, 0, stream>>>(row_start, bedges2, Tc, Tp, Tn, 2.f, -1.f);
        gemm_mfma_kernel<16, 1><<<gemm_blocks, 256, 0, stream>>>(Tn, Wt + (size_t)k * 64 * 512, bias, out);
        ushort* t = Tp; Tp = Tc; Tc = Tn; Tn = t;
    }
}

// Round 7
// 817.516 us; speedup vs baseline: 8.6387x; 1.0747x over previous
//
#include <hip/hip_runtime.h>
#include <hip/hip_bf16.h>

// Problem constants (from setup_inputs)
#define N_NODES 20000
#define NANG 8
#define CH 64                      // in_size == out_size == 64
#define M_ROWS (NANG * N_NODES)    // 160000
#define E_EDGES (M_ROWS * 16)      // 2560000
#define K_CHEB 8
#define WK_STRIDE (NANG * CH * CH) // 32768 floats per weight[k]
#define BROWS 64                   // rows per bucket
#define NB (M_ROWS / BROWS)        // 2500 buckets
#define NCHUNK 320
#define CHUNK (E_EDGES / NCHUNK)   // 8000

typedef short short8 __attribute__((ext_vector_type(8)));
typedef float f32x4 __attribute__((ext_vector_type(4)));

__device__ __forceinline__ float bf2f(ushort u) {
    return __uint_as_float((unsigned int)u << 16);
}

// ---------------- deterministic bucket build (no global atomics) ----------------

// per-(chunk,bucket) histogram
__global__ __launch_bounds__(256) void count_kernel(const int* __restrict__ rows,
                                                    int* __restrict__ chunk_cnt) {
    __shared__ int h[NB];
    int c = blockIdx.x, tid = threadIdx.x;
    for (int i = tid; i < NB; i += 256) h[i] = 0;
    __syncthreads();
    int base = c * CHUNK;
    for (int i = tid; i < CHUNK; i += 256) atomicAdd(&h[rows[base + i] >> 6], 1);
    __syncthreads();
    for (int i = tid; i < NB; i += 256) chunk_cnt[(size_t)c * NB + i] = h[i];
}

__global__ void btotal_kernel(const int* __restrict__ chunk_cnt, int* __restrict__ btotal) {
    int b = blockIdx.x * 256 + threadIdx.x;
    if (b >= NB) return;
    int s = 0;
    for (int c = 0; c < NCHUNK; ++c) s += chunk_cnt[(size_t)c * NB + b];
    btotal[b] = s;
}

// single-block exclusive scan over NB bucket totals (3 per thread; 3072 >= 2500)
__global__ void bscan_kernel(const int* __restrict__ btotal, int* __restrict__ bstart) {
    __shared__ int s[1024];
    int t = threadIdx.x;
    int base = t * 3;
    int c0 = (base     < NB) ? btotal[base]     : 0;
    int c1 = (base + 1 < NB) ? btotal[base + 1] : 0;
    int c2 = (base + 2 < NB) ? btotal[base + 2] : 0;
    int tot = c0 + c1 + c2;
    s[t] = tot;
    __syncthreads();
    for (int off = 1; off < 1024; off <<= 1) {
        int v = (t >= off) ? s[t - off] : 0;
        __syncthreads();
        s[t] += v;
        __syncthreads();
    }
    int pre = s[t] - tot;
    if (base     < NB) bstart[base]     = pre;
    if (base + 1 < NB) bstart[base + 1] = pre + c0;
    if (base + 2 < NB) bstart[base + 2] = pre + c0 + c1;
    if (t == 1023) bstart[NB] = s[1023];
}

// chunk_cnt -> per-(chunk,bucket) write offsets, in place
__global__ void offs_kernel(int* __restrict__ chunk_cnt, const int* __restrict__ bstart) {
    int b = blockIdx.x * 256 + threadIdx.x;
    if (b >= NB) return;
    int run = bstart[b];
    for (int c = 0; c < NCHUNK; ++c) {
        int v = chunk_cnt[(size_t)c * NB + b];
        chunk_cnt[(size_t)c * NB + b] = run;
        run += v;
    }
}

// scatter into bucket-ordered streams (LDS-local offsets, sequential per-bucket writes)
__global__ __launch_bounds__(256) void scatter_kernel(
        const int* __restrict__ rows, const int* __restrict__ cols,
        const float* __restrict__ vals, const int* __restrict__ chunk_cnt,
        int2* __restrict__ bedges) {
    __shared__ int loff[NB];
    int c = blockIdx.x, tid = threadIdx.x;
    for (int i = tid; i < NB; i += 256) loff[i] = chunk_cnt[(size_t)c * NB + i];
    __syncthreads();
    int base = c * CHUNK;
    for (int i = tid; i < CHUNK; i += 256) {
        int e = base + i;
        int r = rows[e];
        int p = atomicAdd(&loff[r >> 6], 1);
        bedges[p] = make_int2(cols[e] | ((r & 63) << 18), __float_as_int(vals[e]));
    }
}

// per-bucket: group edges by row (no col sort — gather order is irrelevant),
// write directly to final CSR slots; emit row_start. Tiny LDS, no insertion sort.
__global__ __launch_bounds__(256) void bucket_group_kernel(
        const int* __restrict__ bstart, const int2* __restrict__ bin,
        int2* __restrict__ bout, int* __restrict__ row_start) {
    __shared__ int cnt[BROWS];
    __shared__ int pref[BROWS];
    __shared__ int fill[BROWS];
    int b = blockIdx.x, tid = threadIdx.x;
    int s = bstart[b], e = bstart[b + 1];
    int n = e - s;
    if (tid < BROWS) cnt[tid] = 0;
    __syncthreads();
    int2 eds[8];                       // cache (n <= 2048 in practice; guarded below)
    int ni = 0;
    for (int i = tid; i < n; i += 256, ++ni) {
        int2 ed = bin[s + i];
        if (ni < 8) eds[ni] = ed;
        atomicAdd(&cnt[(ed.x >> 18) & 63], 1);
    }
    __syncthreads();
    if (tid == 0) {
        int run = 0;
#pragma unroll
        for (int r = 0; r < BROWS; ++r) { pref[r] = run; run += cnt[r]; }
    }
    __syncthreads();
    if (tid < BROWS) fill[tid] = pref[tid];
    __syncthreads();
    ni = 0;
    for (int i = tid; i < n; i += 256, ++ni) {
        int2 ed = (ni < 8) ? eds[ni] : bin[s + i];
        int p = atomicAdd(&fill[(ed.x >> 18) & 63], 1);
        bout[s + p] = make_int2(ed.x & 0x3ffff, ed.y);
    }
    if (tid < BROWS) row_start[b * BROWS + tid] = s + pref[tid];
    if (b == NB - 1 && tid == 0) row_start[M_ROWS] = e;
}

// ---------------- small converts ----------------

__global__ void xconv_kernel(const float* __restrict__ x, ushort* __restrict__ xb) {
    int i = blockIdx.x * 256 + threadIdx.x;
    __hip_bfloat16 v = __float2bfloat16(x[i]);
    xb[i] = *(ushort*)&v;
}

// Wt[k][n][kk] = bf16(W[k][kk][n])
__global__ void wconv_kernel(const float* __restrict__ W, ushort* __restrict__ Wt) {
    int idx = blockIdx.x * 256 + threadIdx.x;
    int kk = idx & 511;
    int n  = (idx >> 9) & 63;
    int k  = idx >> 15;
    __hip_bfloat16 v = __float2bfloat16(W[(size_t)k * WK_STRIDE + kk * 64 + n]);
    Wt[idx] = *(ushort*)&v;
}

// Wsum[n][ck] = bf16( sum_a W[0][a*64+ck][n] )  (tile(x)@W0 == x@Wsum)
__global__ void wsum_kernel(const float* __restrict__ W, ushort* __restrict__ Wsum) {
    int idx = blockIdx.x * 256 + threadIdx.x;
    int ck = idx & 63;
    int n  = idx >> 6;
    float s = 0.f;
#pragma unroll
    for (int a = 0; a < NANG; ++a) s += W[(a * 64 + ck) * 64 + n];
    __hip_bfloat16 v = __float2bfloat16(s);
    Wsum[idx] = *(ushort*)&v;
}

// ---------------- SpMM: row-per-wave gather, readlane edge broadcast ----------------
// One 128B coalesced load pulls 16 edges; readlane(i) makes (col,w) wave-uniform
// SGPRs; 16 independent gathers issue per batch (MLP 16).
// TIN_TILED: Tin is xb [N,64], col % N_NODES. TSUB_MODE: 0 none, 1 [M,64], 2 xb tiled.

template <int TIN_TILED, int TSUB_MODE>
__global__ __launch_bounds__(256) void spmm_kernel(
        const int* __restrict__ row_start, const int2* __restrict__ edges,
        const ushort* __restrict__ Tin, const ushort* __restrict__ Tsub,
        ushort* __restrict__ Tout, float alpha, float beta) {
    int r = (blockIdx.x * 256 + threadIdx.x) >> 6;
    int lane = threadIdx.x & 63;
    if (r >= M_ROWS) return;
    int s = row_start[r];
    int e = row_start[r + 1];
    float acc = 0.f;
    for (int base = s; base < e; base += 16) {
        int idx = min(base + (lane & 15), e - 1);
        int2 ed = edges[idx];                 // 16 edges, 128B coalesced (4x dup)
#pragma unroll
        for (int i = 0; i < 16; ++i) {
            int   col = __builtin_amdgcn_readlane(ed.x, i);
            float w   = __int_as_float(__builtin_amdgcn_readlane(ed.y, i));
            if (base + i >= e) w = 0.f;       // clamped dup edge contributes 0
            unsigned c = (unsigned)col;
            if (TIN_TILED) c %= N_NODES;
            float t = bf2f(Tin[(size_t)c * CH + lane]);
            acc = fmaf(w, t, acc);
        }
    }
    size_t oi = (size_t)r * CH + lane;
    float v = alpha * acc;
    if (TSUB_MODE == 1) v += beta * bf2f(Tsub[oi]);
    if (TSUB_MODE == 2) v += beta * bf2f(Tsub[(size_t)((unsigned)r % N_NODES) * CH + lane]);
    __hip_bfloat16 o = __float2bfloat16(v);
    Tout[oi] = *(ushort*)&o;
}

// ---------------- GEMM via MFMA: out (+)= feat(T) @ Wk (+ bias) ----------------
// C/D layout: col=lane&15, row=(lane>>4)*4+reg  [m89-verified]

template <int KSTEPS, int ACC>
__global__ __launch_bounds__(256) void gemm_mfma_kernel(
        const ushort* __restrict__ T,
        const ushort* __restrict__ Wp,    // [64][KSTEPS*32] bf16
        const float* __restrict__ bias,
        float* __restrict__ out) {        // [N_NODES, 64] fp32
    const int KSTRIDE = KSTEPS * 32;
    int wave = (blockIdx.x * 256 + threadIdx.x) >> 6;
    int l = threadIdx.x & 63;
    int m0 = wave * 16;
    if (m0 >= N_NODES) return;
    int lm = l & 15;
    int lq = l >> 4;

    f32x4 acc[4];
#pragma unroll
    for (int t = 0; t < 4; ++t) acc[t] = (f32x4){0.f, 0.f, 0.f, 0.f};

#pragma unroll
    for (int ks = 0; ks < KSTEPS; ++ks) {
        int a  = ks >> 1;
        int c0 = (ks & 1) * 32;
        short8 af = *(const short8*)(T + ((size_t)(a * N_NODES + m0 + lm)) * CH + c0 + lq * 8);
#pragma unroll
        for (int t = 0; t < 4; ++t) {
            short8 bfrag = *(const short8*)(Wp + (size_t)(t * 16 + lm) * KSTRIDE + ks * 32 + lq * 8);
            acc[t] = __builtin_amdgcn_mfma_f32_16x16x32_bf16(af, bfrag, acc[t], 0, 0, 0);
        }
    }

#pragma unroll
    for (int t = 0; t < 4; ++t) {
        int col = t * 16 + lm;
#pragma unroll
        for (int rI = 0; rI < 4; ++rI) {
            int row = m0 + lq * 4 + rI;
            size_t oi = (size_t)row * CH + col;
            if (ACC) out[oi] += acc[t][rI];
            else     out[oi] = acc[t][rI] + bias[col];
        }
    }
}

// ---------------- launch ----------------

extern "C" void kernel_launch(void* const* d_in, const int* in_sizes, int n_in,
                              void* d_out, int out_size, void* d_ws, size_t ws_size,
                              hipStream_t stream) {
    (void)in_sizes; (void)n_in; (void)out_size; (void)ws_size;
    const float* x       = (const float*)d_in[0];
    const float* ls_vals = (const float*)d_in[1];
    const float* weight  = (const float*)d_in[2];
    const float* bias    = (const float*)d_in[3];
    const int*   ls_rows = (const int*)d_in[4];
    const int*   ls_cols = (const int*)d_in[5];
    float* out = (float*)d_out;

    char* ws = (char*)d_ws;
    size_t off = 0;
    auto alloc = [&](size_t bytes) -> void* {
        void* p = ws + off;
        off += (bytes + 255) & ~(size_t)255;
        return p;
    };
    int*  chunk_cnt = (int*)alloc((size_t)NCHUNK * NB * sizeof(int));
    int*  btotal    = (int*)alloc(NB * sizeof(int));
    int*  bstart    = (int*)alloc((NB + 1) * sizeof(int));
    int*  row_start = (int*)alloc((M_ROWS + 1) * sizeof(int));
    int2* bedges    = (int2*)alloc((size_t)E_EDGES * sizeof(int2));
    int2* bedges2   = (int2*)alloc((size_t)E_EDGES * sizeof(int2));
    ushort* Wt   = (ushort*)alloc((size_t)K_CHEB * 64 * 512 * sizeof(ushort));
    ushort* Wsum = (ushort*)alloc(64 * 64 * sizeof(ushort));
    ushort* xb   = (ushort*)alloc((size_t)N_NODES * CH * sizeof(ushort));
    ushort* T1   = (ushort*)alloc((size_t)M_ROWS * CH * sizeof(ushort));
    ushort* T2   = (ushort*)alloc((size_t)M_ROWS * CH * sizeof(ushort));
    ushort* T3   = (ushort*)alloc((size_t)M_ROWS * CH * sizeof(ushort));

    const int gemm_blocks = (N_NODES / 16 + 3) / 4;   // 313
    const int spmm_blocks = M_ROWS / 4;               // 40000

    // deterministic bucket build + per-bucket row grouping
    count_kernel<<<NCHUNK, 256, 0, stream>>>(ls_rows, chunk_cnt);
    btotal_kernel<<<(NB + 255) / 256, 256, 0, stream>>>(chunk_cnt, btotal);
    bscan_kernel<<<1, 1024, 0, stream>>>(btotal, bstart);
    offs_kernel<<<(NB + 255) / 256, 256, 0, stream>>>(chunk_cnt, bstart);
    scatter_kernel<<<NCHUNK, 256, 0, stream>>>(ls_rows, ls_cols, ls_vals, chunk_cnt, bedges);
    bucket_group_kernel<<<NB, 256, 0, stream>>>(bstart, bedges, bedges2, row_start);

    // converts
    xconv_kernel<<<(N_NODES * CH) / 256, 256, 0, stream>>>(x, xb);
    wconv_kernel<<<(K_CHEB * 64 * 512) / 256, 256, 0, stream>>>(weight, Wt);
    wsum_kernel<<<(64 * 64) / 256, 256, 0, stream>>>(weight, Wsum);

    // k=0: out = x @ Wsum + bias
    gemm_mfma_kernel<2, 0><<<gemm_blocks, 256, 0, stream>>>(xb, Wsum, bias, out);

    // k=1: T1 = L @ tile(x)  (gathers from L2-resident xb); out += feat(T1) @ W1
    spmm_kernel<1, 0><<<spmm_blocks, 256, 0, stream>>>(row_start, bedges2, xb, xb, T1, 1.f, 0.f);
    gemm_mfma_kernel<16, 1><<<gemm_blocks, 256, 0, stream>>>(T1, Wt + (size_t)1 * 64 * 512, bias, out);

    // k=2: T2 = 2 L T1 - tile(x)
    spmm_kernel<0, 2><<<spmm_blocks, 256, 0, stream>>>(row_start, bedges2, T1, xb, T2, 2.f, -1.f);
    gemm_mfma_kernel<16, 1><<<gemm_blocks, 256, 0, stream>>>(T2, Wt + (size_t)2 * 64 * 512, bias, out);

    // k=3..7: Tn = 2 L Tc - Tp
    ushort* Tp = T1;
    ushort* Tc = T2;
    ushort* Tn = T3;
    for (int k = 3; k < K_CHEB; ++k) {
        spmm_kernel<0, 1><<<spmm_blocks, 256, 0, stream>>>(row_start, bedges2, Tc, Tp, Tn, 2.f, -1.f);
        gemm_mfma_kernel<16, 1><<<gemm_blocks, 256, 0, stream>>>(Tn, Wt + (size_t)k * 64 * 512, bias, out);
        ushort* t = Tp; Tp = Tc; Tc = Tn; Tn = t;
    }
}